// Round 1
// baseline (115.244 us; speedup 1.0000x reference)
//
#include <hip/hip_runtime.h>
#include <math.h>

#define NP 4
#define NN 8192
#define NM 8192

// ws layout (float units):
//   PKA: cad_t packed float4 (x,y,z,h) per point   at 0       (131072)
//   PKB: cam packed float4 per point               at 131072  (131072)
//   PRA: cad_t PAIRED: per pair {x0,x1,y0,y1},{z0,z1,h0,h1}  (131072)
//   PRB: cam PAIRED                                           (131072)
//   PART: partial mins [8 z][64 y][8192 q]                    (4194304)
// total ws use: 4718592 floats = 18.9 MB
#define PKA_OFF 0
#define PKB_OFF 131072
#define PRA_OFF 262144
#define PRB_OFF 393216
#define MINS_OFF 524288

#define TQ 8        // queries per thread
#define QT 2048     // queries per block (256 * TQ)
#define SPLITS 64   // target-dim splits -> grid (4,64,8) = 2048 blocks
#define SPAN 128    // targets per block (== NN/SPLITS)

typedef float float2v __attribute__((ext_vector_type(2)));
typedef float float4v __attribute__((ext_vector_type(4)));

__device__ inline float min3f(float a, float b, float c) {
    float d;
    asm("v_min3_f32 %0, %1, %2, %3" : "=v"(d) : "v"(a), "v"(b), "v"(c));
    return d;
}

// Packed fp32 FMA: d.lo = a.lo*b.lo+c.lo ; d.hi = a.hi*b.hi+c.hi (1 inst).
__device__ inline float2v pk_fma(float2v a, float2v b, float2v c) {
    float2v d;
    asm("v_pk_fma_f32 %0, %1, %2, %3" : "=v"(d) : "v"(a), "v"(b), "v"(c));
    return d;
}

__device__ inline void make_transform(const float* __restrict__ quat,
                                      const float* __restrict__ tra,
                                      int p, float T[12]) {
    float q0 = quat[p * 4 + 0], q1 = quat[p * 4 + 1];
    float q2 = quat[p * 4 + 2], q3 = quat[p * 4 + 3];
    float inv = 1.0f / sqrtf(q0 * q0 + q1 * q1 + q2 * q2 + q3 * q3);
    float a = q0 * inv, b = q1 * inv, c = q2 * inv, d = q3 * inv;
    T[0] = 1.0f - 2.0f * c * c - 2.0f * d * d;
    T[1] = 2.0f * b * c - 2.0f * a * d;
    T[2] = 2.0f * a * c + 2.0f * b * d;
    T[3] = tra[p * 3 + 0];
    T[4] = 2.0f * b * c + 2.0f * a * d;
    T[5] = 1.0f - 2.0f * b * b - 2.0f * d * d;
    T[6] = 2.0f * c * d - 2.0f * a * b;
    T[7] = tra[p * 3 + 1];
    T[8] = 2.0f * b * d - 2.0f * a * c;
    T[9] = 2.0f * a * b + 2.0f * c * d;
    T[10] = 1.0f - 2.0f * b * b - 2.0f * c * c;
    T[11] = tra[p * 3 + 2];
}

// 256 blocks x 256 threads over 65536 points: packed float4 (query use),
// PAIRED layout (target use), transforms out, out[0]=0.
// NOTE: no partial-min init needed -- every partial slot is written
// unconditionally (exactly once) by chamfer_kernel.
__global__ __launch_bounds__(256) void prep_kernel(
    const float* __restrict__ cam, const float* __restrict__ cad,
    const float* __restrict__ quat, const float* __restrict__ tra,
    float* __restrict__ ws, float* __restrict__ out) {
    int idx = blockIdx.x * 256 + threadIdx.x;  // [0, 65536)

    float vx, vy, vz;
    int pkoff, proff, local;
    if (idx < NP * NM) {
        int p = idx >> 13;
        float T[12];
        make_transform(quat, tra, p, T);
        float x = cad[idx * 3 + 0];
        float y = cad[idx * 3 + 1];
        float z = cad[idx * 3 + 2];
        vx = fmaf(T[0], x, fmaf(T[1], y, fmaf(T[2], z, T[3])));
        vy = fmaf(T[4], x, fmaf(T[5], y, fmaf(T[6], z, T[7])));
        vz = fmaf(T[8], x, fmaf(T[9], y, fmaf(T[10], z, T[11])));
        pkoff = PKA_OFF;
        proff = PRA_OFF;
        local = idx;
    } else {
        int k = idx - NP * NM;
        vx = cam[k * 3 + 0];
        vy = cam[k * 3 + 1];
        vz = cam[k * 3 + 2];
        pkoff = PKB_OFF;
        proff = PRB_OFF;
        local = k;
    }
    float h = 0.5f * (vx * vx + vy * vy + vz * vz);
    ((float4*)(ws + pkoff))[local] = make_float4(vx, vy, vz, h);
    // paired layout: pair pp=local>>1, lane=local&1:
    //   quad 2pp   = {x0,x1,y0,y1}; quad 2pp+1 = {z0,z1,h0,h1}
    int lane = local & 1;
    size_t f = (size_t)proff + (size_t)(local & ~1) * 4;  // = (2pp)*4 floats
    ws[f + lane] = vx;
    ws[f + 2 + lane] = vy;
    ws[f + 4 + lane] = vz;
    ws[f + 6 + lane] = h;

    if (idx < 64) {
        int p2 = idx >> 4;
        int r = (idx >> 2) & 3;
        int c = idx & 3;
        float T[12];
        make_transform(quat, tra, p2, T);
        float v;
        if (r == 3)
            v = (c == 3) ? 1.0f : 0.0f;
        else
            v = T[r * 4 + c];
        out[1 + idx] = v;
    } else if (idx == 64) {
        out[0] = 0.0f;
    }
}

// grid (4, 64, 8) = 2048 blocks. Targets staged to LDS in the PAIRED layout
// (broadcast reads, conflict-free, 1 ds_read_b128 per target).
// v_pk_fma_f32 computes 2 targets per instruction: per 2 pairs =
// 3 pk_fma + 1 min3 = 2.0 VALU inst/pair.
// Epilogue: PLAIN coalesced store of this block's partial min per query --
// each (z, y, q) slot is owned by exactly one block, so no atomics needed.
// (Previous version did 4.19M device-scope atomicMin here; suspected
// cross-XCD atomic serialization was the dominant cost.)
__global__ __launch_bounds__(256)
__attribute__((amdgpu_waves_per_eu(2, 4)))
void chamfer_kernel(const float* __restrict__ ws, float* __restrict__ part) {
    int tid = threadIdx.x;
    int p = blockIdx.z >> 1;
    int role = blockIdx.z & 1;

    const float4* Q;
    const float4v* T;
    if (role == 0) {  // queries = cad_t, targets = cam
        Q = (const float4*)(ws + PKA_OFF) + p * NM;
        T = (const float4v*)(ws + PRB_OFF) + p * NN;  // 1 float4 per point
    } else {          // queries = cam, targets = cad_t
        Q = (const float4*)(ws + PKB_OFF) + p * NN;
        T = (const float4v*)(ws + PRA_OFF) + p * NM;
    }
    // partial slice owned by this block: [z][y][q0 .. q0+QT)
    float* po = part + (((size_t)blockIdx.z * SPLITS + blockIdx.y) << 13);

    __shared__ float4v sQd[SPAN];  // paired quads: [2pp]=XY, [2pp+1]=ZH

    const float INF = __uint_as_float(0x7f800000u);
    int q0 = blockIdx.x * QT + tid;
    float2v nqx[TQ], nqy[TQ], nqz[TQ];
    float qw[TQ], tmin[TQ];
#pragma unroll
    for (int k = 0; k < TQ; ++k) {
        float4 v = Q[q0 + k * 256];
        nqx[k] = (float2v){-v.x, -v.x};
        nqy[k] = (float2v){-v.y, -v.y};
        nqz[k] = (float2v){-v.z, -v.z};
        qw[k] = v.w;
        tmin[k] = INF;
    }

    int tbase = blockIdx.y * SPAN;  // float4-quad index == point index here
    if (tid < SPAN) sQd[tid] = T[tbase + tid];
    __syncthreads();

    float4v cXY = sQd[0], cZH = sQd[1];
#pragma unroll 2
    for (int pp = 0; pp < SPAN / 2; ++pp) {
        int pn = (pp + 1) & (SPAN / 2 - 1);  // last iter reloads pair 0
        float4v nXY = sQd[2 * pn];
        float4v nZH = sQd[2 * pn + 1];

        float2v X = __builtin_shufflevector(cXY, cXY, 0, 1);
        float2v Y = __builtin_shufflevector(cXY, cXY, 2, 3);
        float2v Z = __builtin_shufflevector(cZH, cZH, 0, 1);
        float2v H = __builtin_shufflevector(cZH, cZH, 2, 3);
#pragma unroll
        for (int k = 0; k < TQ; ++k) {
            float2v s = pk_fma(nqx[k], X, pk_fma(nqy[k], Y, pk_fma(nqz[k], Z, H)));
            tmin[k] = min3f(tmin[k], s.x, s.y);
        }
        cXY = nXY;
        cZH = nZH;
    }

#pragma unroll
    for (int k = 0; k < TQ; ++k) {
        float d2 = 2.0f * (qw[k] + tmin[k]);
        po[q0 + k * 256] = fmaxf(d2, 0.0f);
    }
}

// 256 blocks x 256 threads: one (z, q) item per thread.
// min over 64 y-split partials (coalesced: at fixed y, lanes read
// contiguous q), then sqrt, weight, and hierarchical sum.
__global__ __launch_bounds__(256) void finalize_kernel(
    const float* __restrict__ ws, const float* __restrict__ w,
    float* __restrict__ out) {
    const float* part = ws + MINS_OFF;
    int i = blockIdx.x * 256 + threadIdx.x;  // [0, 65536)
    int tid = threadIdx.x;
    int z = i >> 13;
    int q = i & 8191;
    const float* base = part + ((size_t)z << 19) + q;  // z * 64 * 8192

    // 4 independent min chains to keep loads in flight
    float m0 = base[(size_t)0 << 13];
    float m1 = base[(size_t)1 << 13];
    float m2 = base[(size_t)2 << 13];
    float m3 = base[(size_t)3 << 13];
#pragma unroll
    for (int y = 4; y < SPLITS; y += 4) {
        m0 = fminf(m0, base[(size_t)(y + 0) << 13]);
        m1 = fminf(m1, base[(size_t)(y + 1) << 13]);
        m2 = fminf(m2, base[(size_t)(y + 2) << 13]);
        m3 = fminf(m3, base[(size_t)(y + 3) << 13]);
    }
    float m = fminf(fminf(m0, m1), fminf(m2, m3));

    float acc = w[z >> 1] * sqrtf(m);

#pragma unroll
    for (int off = 32; off > 0; off >>= 1) acc += __shfl_down(acc, off, 64);

    __shared__ float wsum[4];
    if ((tid & 63) == 0) wsum[tid >> 6] = acc;
    __syncthreads();
    if (tid == 0) {
        float blocksum = (wsum[0] + wsum[1] + wsum[2] + wsum[3]) * (1.0f / 8192.0f);
        atomicAdd(out, blocksum);
    }
}

extern "C" void kernel_launch(void* const* d_in, const int* in_sizes, int n_in,
                              void* d_out, int out_size, void* d_ws, size_t ws_size,
                              hipStream_t stream) {
    const float* cam = (const float*)d_in[0];   // (P, N, 3)
    const float* cad = (const float*)d_in[1];   // (P, M, 3)
    const float* w = (const float*)d_in[2];     // (P,)
    const float* quat = (const float*)d_in[3];  // (P, 4)
    const float* tra = (const float*)d_in[4];   // (P, 3, 1)
    float* out = (float*)d_out;
    float* ws = (float*)d_ws;

    prep_kernel<<<256, 256, 0, stream>>>(cam, cad, quat, tra, ws, out);

    dim3 grid(NM / QT, SPLITS, 2 * NP);
    chamfer_kernel<<<grid, 256, 0, stream>>>(ws, ws + MINS_OFF);

    finalize_kernel<<<256, 256, 0, stream>>>(ws, w, out);
}

// Round 2
// 108.027 us; speedup vs baseline: 1.0668x; 1.0668x over previous
//
#include <hip/hip_runtime.h>
#include <math.h>

#define NP 4
#define NN 8192
#define NM 8192

// ws layout (float units):
//   PART: partial mins [8 z][SPLITS y][8192 q]  at 0  (2097152 floats = 8.4 MB)
#define TQ 8        // queries per thread
#define QT 2048     // queries per block (256 * TQ)
#define SPLITS 32   // target-dim splits -> grid (4,32,8) = 1024 blocks = 4/CU
#define SPAN 256    // targets per block (== NN/SPLITS)

typedef float float2v __attribute__((ext_vector_type(2)));
typedef float float4v __attribute__((ext_vector_type(4)));

__device__ inline float min3f(float a, float b, float c) {
    float d;
    asm("v_min3_f32 %0, %1, %2, %3" : "=v"(d) : "v"(a), "v"(b), "v"(c));
    return d;
}

// Packed fp32 FMA: d.lo = a.lo*b.lo+c.lo ; d.hi = a.hi*b.hi+c.hi (1 inst).
// NOTE: measured half-rate (4cy) -- no throughput win over scalar v_fma, but
// halves instruction count (fewer fetch/decode slots) and register moves.
__device__ inline float2v pk_fma(float2v a, float2v b, float2v c) {
    float2v d;
    asm("v_pk_fma_f32 %0, %1, %2, %3" : "=v"(d) : "v"(a), "v"(b), "v"(c));
    return d;
}

__device__ inline void make_transform(const float* __restrict__ quat,
                                      const float* __restrict__ tra,
                                      int p, float T[12]) {
    float q0 = quat[p * 4 + 0], q1 = quat[p * 4 + 1];
    float q2 = quat[p * 4 + 2], q3 = quat[p * 4 + 3];
    float inv = 1.0f / sqrtf(q0 * q0 + q1 * q1 + q2 * q2 + q3 * q3);
    float a = q0 * inv, b = q1 * inv, c = q2 * inv, d = q3 * inv;
    T[0] = 1.0f - 2.0f * c * c - 2.0f * d * d;
    T[1] = 2.0f * b * c - 2.0f * a * d;
    T[2] = 2.0f * a * c + 2.0f * b * d;
    T[3] = tra[p * 3 + 0];
    T[4] = 2.0f * b * c + 2.0f * a * d;
    T[5] = 1.0f - 2.0f * b * b - 2.0f * d * d;
    T[6] = 2.0f * c * d - 2.0f * a * b;
    T[7] = tra[p * 3 + 1];
    T[8] = 2.0f * b * d - 2.0f * a * c;
    T[9] = 2.0f * a * b + 2.0f * c * d;
    T[10] = 1.0f - 2.0f * b * b - 2.0f * c * c;
    T[11] = tra[p * 3 + 2];
}

// Fused prep+chamfer. grid (4, 32, 8) = 1024 blocks (exactly 4 blocks/CU, one
// resident round, no time-slice tail). Each block:
//  - recomputes the transform inline (redundant VALU ~0.8us chip-wide; saves a
//    whole prep kernel launch + 2.4MB staging round-trip)
//  - stages its SPAN targets to LDS in PAIRED layout {x0,x1,y0,y1},{z0,z1,h0,h1}
//    (wave-uniform broadcast reads, conflict-free)
//  - 3 pk_fma + 1 min3 per 2 (q,t) pairs in the inner loop
//  - plain coalesced store of partial mins (slot owned by exactly one block)
// Block (0,0,0) additionally emits the transforms output and zeroes out[0].
__global__ __launch_bounds__(256, 4)
void chamfer_kernel(const float* __restrict__ cam, const float* __restrict__ cad,
                    const float* __restrict__ quat, const float* __restrict__ tra,
                    float* __restrict__ part, float* __restrict__ out) {
    int tid = threadIdx.x;
    int p = blockIdx.z >> 1;
    int role = blockIdx.z & 1;

    float T[12];
    make_transform(quat, tra, p, T);

    if (blockIdx.x == 0 && blockIdx.y == 0 && blockIdx.z == 0) {
        if (tid < 64) {
            int p2 = tid >> 4;
            int r = (tid >> 2) & 3;
            int c = tid & 3;
            float T2[12];
            make_transform(quat, tra, p2, T2);
            float v;
            if (r == 3)
                v = (c == 3) ? 1.0f : 0.0f;
            else
                v = T2[r * 4 + c];
            out[1 + tid] = v;
        } else if (tid == 64) {
            out[0] = 0.0f;
        }
    }

    // ---- stage SPAN targets into LDS (paired layout), transform if cad ----
    // role==0: queries = cad_t, targets = cam ; role==1: queries = cam, targets = cad_t
    __shared__ float sQf[SPAN * 4];
    {
        int j = tid;  // SPAN == blockDim.x
        const float* src = (role ? cad : cam) +
                           ((size_t)p * 8192 + blockIdx.y * SPAN + j) * 3;
        float x = src[0], y = src[1], z = src[2];
        float vx, vy, vz;
        if (role) {
            vx = fmaf(T[0], x, fmaf(T[1], y, fmaf(T[2], z, T[3])));
            vy = fmaf(T[4], x, fmaf(T[5], y, fmaf(T[6], z, T[7])));
            vz = fmaf(T[8], x, fmaf(T[9], y, fmaf(T[10], z, T[11])));
        } else {
            vx = x; vy = y; vz = z;
        }
        float h = 0.5f * (vx * vx + vy * vy + vz * vz);
        int lane = j & 1;
        int f = (j & ~1) * 4;  // pair pp=j>>1: quad 2pp = {x0,x1,y0,y1}, 2pp+1 = {z0,z1,h0,h1}
        sQf[f + lane] = vx;
        sQf[f + 2 + lane] = vy;
        sQf[f + 4 + lane] = vz;
        sQf[f + 6 + lane] = h;
    }

    // ---- load + transform TQ queries per thread ----
    const float INF = __uint_as_float(0x7f800000u);
    int q0 = blockIdx.x * QT + tid;
    const float* qbase = (role ? cam : cad) + (size_t)p * 8192 * 3;
    float2v nqx[TQ], nqy[TQ], nqz[TQ];
    float qw[TQ], tmin[TQ];
#pragma unroll
    for (int k = 0; k < TQ; ++k) {
        const float* s = qbase + (size_t)(q0 + k * 256) * 3;
        float x = s[0], y = s[1], z = s[2];
        float vx, vy, vz;
        if (!role) {
            vx = fmaf(T[0], x, fmaf(T[1], y, fmaf(T[2], z, T[3])));
            vy = fmaf(T[4], x, fmaf(T[5], y, fmaf(T[6], z, T[7])));
            vz = fmaf(T[8], x, fmaf(T[9], y, fmaf(T[10], z, T[11])));
        } else {
            vx = x; vy = y; vz = z;
        }
        float h = 0.5f * (vx * vx + vy * vy + vz * vz);
        nqx[k] = (float2v){-vx, -vx};
        nqy[k] = (float2v){-vy, -vy};
        nqz[k] = (float2v){-vz, -vz};
        qw[k] = h;
        tmin[k] = INF;
    }
    __syncthreads();

    const float4v* sQd = (const float4v*)sQf;
    float4v cXY = sQd[0], cZH = sQd[1];
#pragma unroll 2
    for (int pp = 0; pp < SPAN / 2; ++pp) {
        int pn = (pp + 1) & (SPAN / 2 - 1);  // last iter reloads pair 0
        float4v nXY = sQd[2 * pn];
        float4v nZH = sQd[2 * pn + 1];

        float2v X = __builtin_shufflevector(cXY, cXY, 0, 1);
        float2v Y = __builtin_shufflevector(cXY, cXY, 2, 3);
        float2v Z = __builtin_shufflevector(cZH, cZH, 0, 1);
        float2v H = __builtin_shufflevector(cZH, cZH, 2, 3);
#pragma unroll
        for (int k = 0; k < TQ; ++k) {
            float2v s = pk_fma(nqx[k], X, pk_fma(nqy[k], Y, pk_fma(nqz[k], Z, H)));
            tmin[k] = min3f(tmin[k], s.x, s.y);
        }
        cXY = nXY;
        cZH = nZH;
    }

    float* po = part + (((size_t)blockIdx.z * SPLITS + blockIdx.y) << 13);
#pragma unroll
    for (int k = 0; k < TQ; ++k) {
        float d2 = 2.0f * (qw[k] + tmin[k]);
        po[q0 + k * 256] = fmaxf(d2, 0.0f);
    }
}

// 256 blocks x 256 threads: one (z, q) item per thread.
// min over SPLITS y-split partials (coalesced: at fixed y, lanes read
// contiguous q), then sqrt, weight, and hierarchical sum into out[0].
__global__ __launch_bounds__(256) void finalize_kernel(
    const float* __restrict__ part, const float* __restrict__ w,
    float* __restrict__ out) {
    int i = blockIdx.x * 256 + threadIdx.x;  // [0, 65536)
    int tid = threadIdx.x;
    int z = i >> 13;
    int q = i & 8191;
    const float* base = part + ((size_t)z * SPLITS << 13) + q;

    // 4 independent min chains to keep loads in flight
    float m0 = base[(size_t)0 << 13];
    float m1 = base[(size_t)1 << 13];
    float m2 = base[(size_t)2 << 13];
    float m3 = base[(size_t)3 << 13];
#pragma unroll
    for (int y = 4; y < SPLITS; y += 4) {
        m0 = fminf(m0, base[(size_t)(y + 0) << 13]);
        m1 = fminf(m1, base[(size_t)(y + 1) << 13]);
        m2 = fminf(m2, base[(size_t)(y + 2) << 13]);
        m3 = fminf(m3, base[(size_t)(y + 3) << 13]);
    }
    float m = fminf(fminf(m0, m1), fminf(m2, m3));

    float acc = w[z >> 1] * sqrtf(m);

#pragma unroll
    for (int off = 32; off > 0; off >>= 1) acc += __shfl_down(acc, off, 64);

    __shared__ float wsum[4];
    if ((tid & 63) == 0) wsum[tid >> 6] = acc;
    __syncthreads();
    if (tid == 0) {
        float blocksum = (wsum[0] + wsum[1] + wsum[2] + wsum[3]) * (1.0f / 8192.0f);
        atomicAdd(out, blocksum);
    }
}

extern "C" void kernel_launch(void* const* d_in, const int* in_sizes, int n_in,
                              void* d_out, int out_size, void* d_ws, size_t ws_size,
                              hipStream_t stream) {
    const float* cam = (const float*)d_in[0];   // (P, N, 3)
    const float* cad = (const float*)d_in[1];   // (P, M, 3)
    const float* w = (const float*)d_in[2];     // (P,)
    const float* quat = (const float*)d_in[3];  // (P, 4)
    const float* tra = (const float*)d_in[4];   // (P, 3, 1)
    float* out = (float*)d_out;
    float* ws = (float*)d_ws;

    dim3 grid(NM / QT, SPLITS, 2 * NP);
    chamfer_kernel<<<grid, 256, 0, stream>>>(cam, cad, quat, tra, ws, out);

    finalize_kernel<<<256, 256, 0, stream>>>(ws, w, out);
}